// Round 1
// baseline (1345.777 us; speedup 1.0000x reference)
//
#include <hip/hip_runtime.h>

// Problem: softmin-weighted retrieval over an address bank.
//   A: [N=131072, D=2048] fp32 (1 GiB), q: [D] fp32
//   sims = (A@q) / max(|A_i||q|, eps); w = softmax(sims/0.1); out = w @ A
//
// Algebra: softmax(-(1-s)/T) == softmax(s/T); since s<=1 we use the FIXED
// shift m=1.0 -> w_i = exp((s_i-1)*10) in [e^-20, 1]: no online max needed,
// so a SINGLE pass over A suffices (read 1 GiB once instead of twice).
//
// k1: each wave streams 64 contiguous rows; per row: 8x float4 loads/lane,
//     dot+norm^2 butterfly-reduced over 64 lanes, acc[32]/lane += w*row.
//     Block combines 4 wave-accumulators in LDS -> 512 partials in d_ws.
// k2: 8x16 blocks reduce 512 partials -> 16 partials.
// k3: 8 blocks reduce 16 partials, divide by total weight L -> out.

#define N_ADDR 131072
#define D 2048
#define TPB 256
#define WPB 4                    // waves per block
#define NB1 512                  // k1 blocks
#define NWAVE (NB1 * WPB)        // 2048 waves
#define ROWS_PER_WAVE (N_ADDR / NWAVE)   // 64
#define PB2 16                   // second-stage partial count
#define P_PER_CHUNK (NB1 / PB2)  // 32
#define EPS 1e-8f
#define TEMP_INV 10.0f

__global__ __launch_bounds__(TPB) void dsdm_k1(
    const float* __restrict__ A, const float* __restrict__ q,
    float* __restrict__ part, float* __restrict__ lpart) {
  const int tid  = threadIdx.x;
  const int lane = tid & 63;
  const int wave = tid >> 6;
  const int gw   = blockIdx.x * WPB + wave;

  // Query fragment: lane holds cols {lane*4 + j*256 .. +3}, j=0..7
  const float4* q4 = (const float4*)q;
  float4 qv[8];
#pragma unroll
  for (int j = 0; j < 8; ++j) qv[j] = q4[lane + 64 * j];

  float qn2 = 0.f;
#pragma unroll
  for (int j = 0; j < 8; ++j)
    qn2 += qv[j].x * qv[j].x + qv[j].y * qv[j].y + qv[j].z * qv[j].z + qv[j].w * qv[j].w;
#pragma unroll
  for (int m = 1; m < 64; m <<= 1) qn2 += __shfl_xor(qn2, m, 64);
  const float qn = sqrtf(qn2);

  float4 acc[8];
#pragma unroll
  for (int j = 0; j < 8; ++j) acc[j] = make_float4(0.f, 0.f, 0.f, 0.f);
  float lsum = 0.f;

  const int row0 = gw * ROWS_PER_WAVE;
  for (int r = 0; r < ROWS_PER_WAVE; ++r) {
    const float4* rv = (const float4*)(A + (size_t)(row0 + r) * D);
    float4 x[8];
#pragma unroll
    for (int j = 0; j < 8; ++j) x[j] = rv[lane + 64 * j];

    float dot = 0.f, n2 = 0.f;
#pragma unroll
    for (int j = 0; j < 8; ++j) {
      dot += x[j].x * qv[j].x + x[j].y * qv[j].y + x[j].z * qv[j].z + x[j].w * qv[j].w;
      n2  += x[j].x * x[j].x + x[j].y * x[j].y + x[j].z * x[j].z + x[j].w * x[j].w;
    }
#pragma unroll
    for (int m = 1; m < 64; m <<= 1) {
      dot += __shfl_xor(dot, m, 64);
      n2  += __shfl_xor(n2, m, 64);
    }

    const float s = dot / fmaxf(sqrtf(n2) * qn, EPS);
    const float w = __expf((s - 1.0f) * TEMP_INV);  // fixed-shift softmax weight
    lsum += w;
#pragma unroll
    for (int j = 0; j < 8; ++j) {
      acc[j].x += w * x[j].x;
      acc[j].y += w * x[j].y;
      acc[j].z += w * x[j].z;
      acc[j].w += w * x[j].w;
    }
  }

  // Block combine: 4 waves -> one partial [D] + one weight sum
  __shared__ float sacc[D];
  __shared__ float sl[WPB];
  for (int k = tid; k < D; k += TPB) sacc[k] = 0.f;
  if (lane == 0) sl[wave] = lsum;
  __syncthreads();
  for (int wv = 0; wv < WPB; ++wv) {
    if (wave == wv) {
#pragma unroll
      for (int j = 0; j < 8; ++j) {
        const int base = lane * 4 + j * 256;
        sacc[base + 0] += acc[j].x;
        sacc[base + 1] += acc[j].y;
        sacc[base + 2] += acc[j].z;
        sacc[base + 3] += acc[j].w;
      }
    }
    __syncthreads();
  }
  float* pout = part + (size_t)blockIdx.x * D;
  for (int k = tid; k < D; k += TPB) pout[k] = sacc[k];
  if (tid == 0) lpart[blockIdx.x] = sl[0] + sl[1] + sl[2] + sl[3];
}

__global__ __launch_bounds__(TPB) void dsdm_k2(
    const float* __restrict__ part, const float* __restrict__ lpart,
    float* __restrict__ part2, float* __restrict__ l2) {
  const int cb = blockIdx.x;  // 0..7 column chunk
  const int pb = blockIdx.y;  // 0..15 partial chunk
  const int c  = cb * TPB + threadIdx.x;
  float s = 0.f;
  for (int i = 0; i < P_PER_CHUNK; ++i)
    s += part[(size_t)(pb * P_PER_CHUNK + i) * D + c];
  part2[(size_t)pb * D + c] = s;
  if (cb == 0 && threadIdx.x == 0) {
    float ls = 0.f;
    for (int i = 0; i < P_PER_CHUNK; ++i) ls += lpart[pb * P_PER_CHUNK + i];
    l2[pb] = ls;
  }
}

__global__ __launch_bounds__(TPB) void dsdm_k3(
    const float* __restrict__ part2, const float* __restrict__ l2,
    float* __restrict__ out) {
  const int c = blockIdx.x * TPB + threadIdx.x;
  float L = 0.f;
#pragma unroll
  for (int i = 0; i < PB2; ++i) L += l2[i];
  float s = 0.f;
#pragma unroll
  for (int i = 0; i < PB2; ++i) s += part2[(size_t)i * D + c];
  out[c] = s / L;
}

extern "C" void kernel_launch(void* const* d_in, const int* in_sizes, int n_in,
                              void* d_out, int out_size, void* d_ws, size_t ws_size,
                              hipStream_t stream) {
  const float* A = (const float*)d_in[0];
  const float* q = (const float*)d_in[1];
  float* out = (float*)d_out;

  // Workspace layout (floats): part[NB1*D] | lpart[NB1] | part2[PB2*D] | l2[PB2]
  float* part  = (float*)d_ws;
  float* lpart = part + (size_t)NB1 * D;
  float* part2 = lpart + NB1;
  float* l2    = part2 + (size_t)PB2 * D;

  dsdm_k1<<<NB1, TPB, 0, stream>>>(A, q, part, lpart);
  dsdm_k2<<<dim3(D / TPB, PB2), TPB, 0, stream>>>(part, lpart, part2, l2);
  dsdm_k3<<<D / TPB, TPB, 0, stream>>>(part2, l2, out);
}